// Round 17
// baseline (1200.260 us; speedup 1.0000x reference)
//
#include <hip/hip_runtime.h>
#include <hip/hip_bf16.h>
#include <math.h>

typedef __hip_bfloat16 bf16;

#define B_   16
#define C_   256
#define H_   64
#define W_   96
#define HW_  6144
#define Q_   300
#define NH_  8
#define DH_  32
#define HID_ 512
#define QB_  4                 // queries/block (qproj, proj_ln, deform)
#define SCALE_ 0.17677669529663687f   // 1/sqrt(32)

__device__ __forceinline__ float b2f(bf16 v){ return __bfloat162float(v); }
__device__ __forceinline__ bf16 f2b(float v){ return __float2bfloat16(v); }
__device__ __forceinline__ int clampi(int v, int lo, int hi){
  return v < lo ? lo : (v > hi ? hi : v);
}

// ---------------------------------------------------------------- scoring MLP (f32, register-tiled)
// 8x8 register tile; hidden in 2 passes of 256; kt-tiles of 16 channels.
// XT=1: writes xt [B,HW,C] as a side-effect of pass-0 staging (the xs tile is
// exactly a [16c][64hw] block of x) — the separate xt_k dispatch and its
// 100MB x re-read are eliminated. Bitwise-identical xt (same staged values).
template<int XT>
__global__ __launch_bounds__(256) void score_k(const float* __restrict__ x,
    const float* __restrict__ w1, const float* __restrict__ b1,
    const float* __restrict__ w2, const float* __restrict__ b2,
    float* __restrict__ logits, float* __restrict__ xt){
  int b = blockIdx.y, hw0 = blockIdx.x*64;
  int tid = threadIdx.x;
  int tc = tid & 31;        // hidden group 0..31 (2x4 wide)
  int tr = tid >> 5;        // hw group 0..7 (8 wide)
  __shared__ float xs[16][68];
  __shared__ float wsl[16][256];
  float (*red)[33] = (float(*)[33])wsl;   // alias: used only after final barrier
  float part[8];
  #pragma unroll
  for (int i=0;i<8;i++) part[i]=0.f;
  for (int pass=0; pass<2; ++pass){
    float acc[8][8];
    #pragma unroll
    for (int i=0;i<8;i++)
      #pragma unroll
      for (int j=0;j<8;j++) acc[i][j]=0.f;
    for (int kt=0; kt<16; ++kt){
      // stage x tile [16 c][64 hw]: 256 float4, 1 per thread
      {
        int e = tid;                    // float4 index 0..255
        int rr4 = e & 15, kk = e >> 4;  // 16 f4 per row, kk 0..15
        *reinterpret_cast<float4*>(&xs[kk][rr4*4]) =
          *reinterpret_cast<const float4*>(&x[(size_t)(b*C_ + kt*16+kk)*HW_ + hw0 + rr4*4]);
      }
      // stage w1 tile [16 c][256 hid]: 1024 float4, 4 per thread
      #pragma unroll
      for (int i=0;i<4;i++){
        int e = tid + i*256;            // float4 index 0..1023
        int jj4 = e & 63, kk = e >> 6;  // 64 f4 per row, kk 0..15
        *reinterpret_cast<float4*>(&wsl[kk][jj4*4]) =
          *reinterpret_cast<const float4*>(&w1[(size_t)(kt*16+kk)*HID_ + pass*256 + jj4*4]);
      }
      __syncthreads();
      // pass-0 side effect: write this tile transposed to xt (coalesces in L2:
      // 4 waves fill adjacent 16B chunks of each 64B line)
      if (XT && pass==0){
        int rr = tid & 63, c4 = tid >> 6;   // rr: hw row, c4: 0..3 (4 c's each)
        float4 v;
        v.x = xs[c4*4+0][rr]; v.y = xs[c4*4+1][rr];
        v.z = xs[c4*4+2][rr]; v.w = xs[c4*4+3][rr];
        *reinterpret_cast<float4*>(&xt[((size_t)b*HW_ + hw0 + rr)*C_ + kt*16 + c4*4]) = v;
      }
      #pragma unroll
      for (int k=0;k<16;k++){
        float4 a0 = *reinterpret_cast<float4*>(&xs[k][tr*8]);
        float4 a1 = *reinterpret_cast<float4*>(&xs[k][tr*8+4]);
        float4 w0 = *reinterpret_cast<float4*>(&wsl[k][tc*4]);
        float4 w4 = *reinterpret_cast<float4*>(&wsl[k][128 + tc*4]);
        float aa[8] = {a0.x,a0.y,a0.z,a0.w,a1.x,a1.y,a1.z,a1.w};
        float ww[8] = {w0.x,w0.y,w0.z,w0.w,w4.x,w4.y,w4.z,w4.w};
        #pragma unroll
        for (int i=0;i<8;i++)
          #pragma unroll
          for (int j=0;j<8;j++)
            acc[i][j] += aa[i]*ww[j];
      }
      __syncthreads();
    }
    // epilogue for this pass: elu + dot with w2 into part[i]
    #pragma unroll
    for (int j=0;j<8;j++){
      int col = (j < 4) ? (tc*4 + j) : (128 + tc*4 + (j-4));
      int jg = pass*256 + col;
      float bb = b1[jg], w2v = w2[jg];
      #pragma unroll
      for (int i=0;i<8;i++){
        float h = acc[i][j] + bb;
        h = h > 0.f ? h : expm1f(h);     // elu
        part[i] += h * w2v;
      }
    }
  }
  // reduce part[8] over the 32 tc groups (red aliases wsl; all reads done)
  #pragma unroll
  for (int i=0;i<8;i++) red[tr*8+i][tc] = part[i];
  __syncthreads();
  if (tid < 64){
    float s = 0.f;
    for (int t=0;t<32;t++) s += red[tid][t];
    logits[(size_t)b*HW_ + hw0 + tid] = s + b2[0];
  }
}

// ---------------------------------------------------------------- top-k (300 of 6144), f32
__global__ __launch_bounds__(1024) void topk_k(const float* __restrict__ logits,
                                               int* __restrict__ idxs){
  int b = blockIdx.x, tid = threadIdx.x;
  __shared__ unsigned long long keys[8192];
  for (int i = tid; i < 8192; i += 1024){
    unsigned long long key = 0ull;                 // pad sorts last
    if (i < HW_){
      float v = logits[(size_t)b*HW_ + i];
      unsigned u = __float_as_uint(v);
      unsigned m = (u & 0x80000000u) ? ~u : (u ^ 0x80000000u);
      if (!(v == v)) m = 0u;                       // NaN sorts last
      key = ((unsigned long long)m << 32) | (unsigned)(HW_ - 1 - i);
    }
    keys[i] = key;
  }
  __syncthreads();
  for (int k = 2; k <= 8192; k <<= 1){
    for (int j = k >> 1; j >= 1; j >>= 1){
      for (int i = tid; i < 8192; i += 1024){
        int l = i ^ j;
        if (l > i){
          unsigned long long a = keys[i], c = keys[l];
          bool sw = ((i & k) == 0) ? (a < c) : (a > c);   // descending overall
          if (sw){ keys[i] = c; keys[l] = a; }
        }
      }
      __syncthreads();
    }
  }
  if (tid < Q_){
    int idx = HW_ - 1 - (int)(keys[tid] & 0xFFFFFFFFull);
    idxs[b*Q_ + tid] = idx;
  }
}

// ---------------------------------------------------------------- fused rp-refs + MHA qkv (4 queries/block)
template<int XT>
__global__ __launch_bounds__(256) void qproj_k(const float* __restrict__ x,
    const float* __restrict__ xt,
    const int* __restrict__ idxs,
    const float* __restrict__ rw1, const float* __restrict__ rb1,
    const float* __restrict__ rw2, const float* __restrict__ rb2,
    const float* __restrict__ mw,  const float* __restrict__ mb,
    float* __restrict__ refs,
    bf16* __restrict__ qarr, bf16* __restrict__ karr, bf16* __restrict__ varr){
  int blk = blockIdx.x;
  int b = blk/(Q_/QB_), q0 = (blk%(Q_/QB_))*QB_;
  int tid = threadIdx.x;
  __shared__ float rowl[QB_][C_];
  __shared__ float hl[QB_][HID_];
  __shared__ float red[16][17];
  int idxv[QB_];
  #pragma unroll
  for (int j=0;j<QB_;j++) idxv[j] = clampi(idxs[b*Q_+q0+j], 0, HW_-1);
  #pragma unroll
  for (int j=0;j<QB_;j++){
    if (XT) rowl[j][tid] = xt[((size_t)b*HW_ + idxv[j])*C_ + tid];
    else    rowl[j][tid] = x[((size_t)b*C_ + tid)*HW_ + idxv[j]];
  }
  __syncthreads();
  // rp hidden (no activation between rp layers)
  float h0[QB_], h1[QB_];
  #pragma unroll
  for (int j=0;j<QB_;j++){ h0[j]=rb1[tid]; h1[j]=rb1[tid+256]; }
  for (int c=0;c<C_;c++){
    float wv0 = rw1[(size_t)c*HID_ + tid];
    float wv1 = rw1[(size_t)c*HID_ + tid + 256];
    #pragma unroll
    for (int j=0;j<QB_;j++){
      float rv = rowl[j][c];
      h0[j] += rv*wv0; h1[j] += rv*wv1;
    }
  }
  #pragma unroll
  for (int j=0;j<QB_;j++){ hl[j][tid]=h0[j]; hl[j][tid+256]=h1[j]; }
  // qkv projection
  float aq[QB_], ak[QB_], av[QB_];
  #pragma unroll
  for (int j=0;j<QB_;j++){ aq[j]=mb[tid]; ak[j]=mb[tid+256]; av[j]=mb[tid+512]; }
  for (int c=0;c<C_;c++){
    const float* wr = mw + (size_t)c*768;
    float w0 = wr[tid], w1v = wr[tid+256], w2v = wr[tid+512];
    #pragma unroll
    for (int j=0;j<QB_;j++){
      float rv = rowl[j][c];
      aq[j] += rv*w0; ak[j] += rv*w1v; av[j] += rv*w2v;
    }
  }
  int h = tid>>5, d = tid&31;
  #pragma unroll
  for (int j=0;j<QB_;j++){
    size_t o = (((size_t)b*NH_+h)*Q_+(q0+j))*DH_ + d;
    qarr[o]=f2b(aq[j]); karr[o]=f2b(ak[j]); varr[o]=f2b(av[j]);
  }
  __syncthreads();   // hl ready
  // rp second layer: 16 outputs per query
  int o = tid & 15, seg = tid >> 4;
  for (int j=0;j<QB_;j++){
    float p = 0.f;
    for (int jj=seg*32; jj<seg*32+32; jj++) p += hl[j][jj]*rw2[jj*16+o];
    red[seg][o] = p;
    __syncthreads();
    if (tid < 16){
      float s = 0.f;
      for (int sg=0; sg<16; sg++) s += red[sg][tid];
      refs[((size_t)b*Q_+(q0+j))*16 + tid] = tanhf(s + rb2[tid]);
    }
    __syncthreads();
  }
}

// ---------------------------------------------------------------- self-attention (per b,h; split in 4)
__global__ __launch_bounds__(256) void attn_k(const bf16* __restrict__ qarr,
    const bf16* __restrict__ karr, const bf16* __restrict__ varr,
    bf16* __restrict__ att_o){
  int blk = blockIdx.x; int bh = blk >> 2, part = blk & 3;
  int tid = threadIdx.x, rg = tid >> 5, lane = tid & 31;
  __shared__ bf16 kk[Q_][34];
  __shared__ bf16 vv[Q_][34];
  __shared__ float ps[8][304];
  __shared__ float qsl[8][32];
  const bf16* kb = karr + (size_t)bh*Q_*DH_;
  const bf16* vb = varr + (size_t)bh*Q_*DH_;
  const bf16* qb = qarr + (size_t)bh*Q_*DH_;
  for (int e=tid; e<Q_*DH_; e+=256){
    int k = e >> 5, d = e & 31;
    kk[k][d] = kb[e];
    vv[k][d] = vb[e];
  }
  __syncthreads();
  int b = bh >> 3, h = bh & 7;
  int rbase = part*75;
  for (int p0=0; p0<75; p0+=8){
    int rr = p0 + rg;
    bool act = rr < 75;
    int r = rbase + (act ? rr : 0);
    float qd = act ? b2f(qb[r*DH_ + lane]) : 0.f;
    qsl[rg][lane] = qd;
    __syncthreads();
    float lmax = -1e30f;
    for (int k=lane; k<Q_; k+=32){
      float s = 0.f;
      #pragma unroll
      for (int d=0; d<DH_; d++) s += qsl[rg][d]*b2f(kk[k][d]);
      s *= SCALE_;
      ps[rg][k] = s;
      lmax = fmaxf(lmax, s);
    }
    #pragma unroll
    for (int off=16; off>=1; off>>=1) lmax = fmaxf(lmax, __shfl_xor(lmax, off, 32));
    float lsum = 0.f;
    for (int k=lane; k<Q_; k+=32){
      float e = expf(ps[rg][k] - lmax);
      ps[rg][k] = e;
      lsum += e;
    }
    #pragma unroll
    for (int off=16; off>=1; off>>=1) lsum += __shfl_xor(lsum, off, 32);
    __syncthreads();
    float out = 0.f;
    for (int k=0;k<Q_;k++) out += ps[rg][k]*b2f(vv[k][lane]);
    if (act) att_o[((size_t)b*Q_ + r)*C_ + h*DH_ + lane] = f2b(out / lsum);
    __syncthreads();
  }
}

// ---------------------------------------------------------------- out-proj + residual + LN + dq (4 queries/block)
template<int XT>
__global__ __launch_bounds__(256) void proj_ln_k(const bf16* __restrict__ att_o,
    const float* __restrict__ x, const float* __restrict__ xt,
    const int* __restrict__ idxs,
    const float* __restrict__ ow, const float* __restrict__ ob,
    const float* __restrict__ g,  const float* __restrict__ beta,
    const float* __restrict__ dqw, const float* __restrict__ dqb,
    float* __restrict__ tgt, float* __restrict__ dqv){
  int blk = blockIdx.x, tid = threadIdx.x;
  int b = blk/(Q_/QB_), q0 = (blk%(Q_/QB_))*QB_;
  __shared__ float ol[QB_][C_];
  __shared__ float yl[QB_][C_];
  __shared__ float rs[QB_][4], rs2[QB_][4];
  #pragma unroll
  for (int j=0;j<QB_;j++)
    ol[j][tid] = b2f(att_o[((size_t)(b*Q_+q0+j))*C_ + tid]);
  __syncthreads();
  float acc[QB_];
  #pragma unroll
  for (int j=0;j<QB_;j++) acc[j] = ob[tid];
  for (int c=0;c<C_;c++){
    float w = ow[(size_t)c*C_+tid];
    #pragma unroll
    for (int j=0;j<QB_;j++) acc[j] += ol[j][c]*w;
  }
  float tv[QB_];
  #pragma unroll
  for (int j=0;j<QB_;j++){
    int idx = clampi(idxs[b*Q_+q0+j], 0, HW_-1);
    float resid;
    if (XT) resid = xt[((size_t)b*HW_ + idx)*C_ + tid];
    else    resid = x[((size_t)b*C_ + tid)*HW_ + idx];
    tv[j] = resid + acc[j];
  }
  // LN per query (4 independent 256-wide reductions)
  #pragma unroll
  for (int j=0;j<QB_;j++){
    float s = tv[j], s2 = tv[j]*tv[j];
    #pragma unroll
    for (int off=32; off>=1; off>>=1){
      s  += __shfl_xor(s,  off, 64);
      s2 += __shfl_xor(s2, off, 64);
    }
    if ((tid&63)==0){ rs[j][tid>>6]=s; rs2[j][tid>>6]=s2; }
  }
  __syncthreads();
  #pragma unroll
  for (int j=0;j<QB_;j++){
    float ts=0.f, ts2=0.f;
    #pragma unroll
    for (int w=0;w<4;w++){ ts+=rs[j][w]; ts2+=rs2[j][w]; }
    float mu = ts*(1.f/256.f);
    float var = ts2*(1.f/256.f) - mu*mu;
    if (!(var > 0.f)) var = 0.f;
    float y = (tv[j]-mu)*rsqrtf(var+1e-5f)*g[tid] + beta[tid];
    tgt[((size_t)(b*Q_+q0+j))*C_ + tid] = y;
    yl[j][tid] = y;
  }
  __syncthreads();
  float a2[QB_];
  #pragma unroll
  for (int j=0;j<QB_;j++) a2[j] = dqb[tid];
  for (int c=0;c<C_;c++){
    float w = dqw[(size_t)c*C_+tid];
    #pragma unroll
    for (int j=0;j<QB_;j++) a2[j] += yl[j][c]*w;
  }
  #pragma unroll
  for (int j=0;j<QB_;j++)
    dqv[((size_t)(b*Q_+q0+j))*C_ + tid] = a2[j];
}

// ---------------------------------------------------------------- deformable attn + final MLPs
// R10/R11-exact — measured-best deform (370-383us across 9 config A/Bs).
template<int XT>
__global__ __launch_bounds__(512) void deform_k(const float* __restrict__ x,
    const float* __restrict__ xt,
    const float* __restrict__ refs, const float* __restrict__ dqv,
    const float* __restrict__ tgt,
    const float* __restrict__ dkw, const float* __restrict__ dkb,
    const float* __restrict__ dvw, const float* __restrict__ dvb,
    const float* __restrict__ pw1, const float* __restrict__ pb1,
    const float* __restrict__ pw2, const float* __restrict__ pb2,
    const float* __restrict__ cw1, const float* __restrict__ cb1,
    const float* __restrict__ cw2, const float* __restrict__ cb2,
    float* __restrict__ out_poly, float* __restrict__ out_cls){
  int blk = blockIdx.x; int b = blk/(Q_/QB_), qg = blk%(Q_/QB_);
  int q0 = qg*QB_;
  int tid = threadIdx.x;
  int col = tid & 255;
  int half = tid >> 8;                               // 0 -> queries 0,1; 1 -> queries 2,3
  __shared__ float smem_u[32*C_];                    // 32KB union region
  float (*rows_l)[C_]  = (float(*)[C_])smem_u;       // [32][256]
  float (*hp)[HID_]    = (float(*)[HID_])smem_u;     // [QB][512] (aliased)
  float (*hc)[HID_]    = (float(*)[HID_])(smem_u + QB_*HID_);
  __shared__ float tl[QB_][C_];        // 4KB
  __shared__ float grefs[32][2];
  __shared__ float redp[16][8];
  __shared__ float redc[16];
  // prefetch refs for all 32 rows (one float per thread, parallel)
  if (tid < 64){
    int rloc = tid >> 1, comp = tid & 1;
    int r = qg*32 + rloc;
    int n = r/Q_, q = r - n*Q_;
    grefs[rloc][comp] = refs[(((size_t)b*Q_+q)*8+n)*2 + comp];
  }
  __syncthreads();
  const float* xc  = x  + ((size_t)b*C_ + col)*HW_;
  const float* xbt = xt + (size_t)b*HW_*C_;
  // gather this half's 16 bilinear-sampled rows (channel col of each)
  for (int i=0; i<16; ++i){
    int rloc = half*16 + i;
    float gx = grefs[rloc][0];
    float gy = grefs[rloc][1];
    if (!(gx > -2.f && gx < 2.f)) gx = 0.f;
    if (!(gy > -2.f && gy < 2.f)) gy = 0.f;
    float ix = (gx + 1.f)*48.f - 0.5f;    // W/2
    float iy = (gy + 1.f)*32.f - 0.5f;    // H/2
    float fx = floorf(ix), fy = floorf(iy);
    int x0 = (int)fx, y0 = (int)fy;
    float wx1 = ix - fx, wy1 = iy - fy;
    float wx0 = 1.f - wx1, wy0 = 1.f - wy1;
    float v = 0.f;
    if (XT){
      if (y0   >= 0 && y0   < H_ && x0   >= 0 && x0   < W_) v += wy0*wx0*xbt[(size_t)(y0*W_+x0)*C_ + col];
      if (y0   >= 0 && y0   < H_ && x0+1 >= 0 && x0+1 < W_) v += wy0*wx1*xbt[(size_t)(y0*W_+x0+1)*C_ + col];
      if (y0+1 >= 0 && y0+1 < H_ && x0   >= 0 && x0   < W_) v += wy1*wx0*xbt[(size_t)((y0+1)*W_+x0)*C_ + col];
      if (y0+1 >= 0 && y0+1 < H_ && x0+1 >= 0 && x0+1 < W_) v += wy1*wx1*xbt[(size_t)((y0+1)*W_+x0+1)*C_ + col];
    } else {
      if (y0   >= 0 && y0   < H_ && x0   >= 0 && x0   < W_) v += wy0*wx0*xc[y0*W_+x0];
      if (y0   >= 0 && y0   < H_ && x0+1 >= 0 && x0+1 < W_) v += wy0*wx1*xc[y0*W_+x0+1];
      if (y0+1 >= 0 && y0+1 < H_ && x0   >= 0 && x0   < W_) v += wy1*wx0*xc[(y0+1)*W_+x0];
      if (y0+1 >= 0 && y0+1 < H_ && x0+1 >= 0 && x0+1 < W_) v += wy1*wx1*xc[(y0+1)*W_+x0+1];
    }
    rows_l[rloc][col] = v;
  }
  __syncthreads();
  // dk/dv projection: this half's 16 rows, register accumulators, c-loop x4
  float ka[16], va[16];
  float kbb = dkb[col], vbb = dvb[col];
  #pragma unroll
  for (int rr=0; rr<16; ++rr){ ka[rr]=kbb; va[rr]=vbb; }
  for (int c=0; c<C_; c+=4){
    float wk0 = dkw[(size_t)(c+0)*C_+col], wk1 = dkw[(size_t)(c+1)*C_+col];
    float wk2 = dkw[(size_t)(c+2)*C_+col], wk3 = dkw[(size_t)(c+3)*C_+col];
    float wv0 = dvw[(size_t)(c+0)*C_+col], wv1 = dvw[(size_t)(c+1)*C_+col];
    float wv2 = dvw[(size_t)(c+2)*C_+col], wv3 = dvw[(size_t)(c+3)*C_+col];
    #pragma unroll
    for (int rr=0; rr<16; ++rr){
      float4 rv = *reinterpret_cast<float4*>(&rows_l[half*16+rr][c]);   // LDS broadcast
      ka[rr] += rv.x*wk0 + rv.y*wk1 + rv.z*wk2 + rv.w*wk3;
      va[rr] += rv.x*wv0 + rv.y*wv1 + rv.z*wv2 + rv.w*wv3;
    }
  }
  // attention: this half's 2 queries (head = col>>5; 32-lane reduce is intra-head)
  #pragma unroll
  for (int jq=0; jq<2; ++jq){
    int jj = half*2 + jq;
    int q2 = q0 + jj;
    float qd = dqv[((size_t)b*Q_+q2)*C_ + col];
    float s[8];
    #pragma unroll
    for (int n=0;n<8;n++){
      float t_ = qd * ka[jq*8+n];
      #pragma unroll
      for (int off=16; off>=1; off>>=1) t_ += __shfl_xor(t_, off, 32);
      s[n] = t_ * SCALE_;
    }
    float m = s[0];
    #pragma unroll
    for (int n=1;n<8;n++) m = fmaxf(m, s[n]);
    float e[8], sum = 0.f;
    #pragma unroll
    for (int n=0;n<8;n++){ e[n] = expf(s[n]-m); sum += e[n]; }
    float inv = 1.f/sum;
    float out = 0.f;
    #pragma unroll
    for (int n=0;n<8;n++) out += e[n]*inv*va[jq*8+n];
    tl[jj][col] = tgt[((size_t)b*Q_+q2)*C_ + col] + out;
  }
  __syncthreads();   // orders: all rows_l reads done; tl ready for all 4 queries
  // final MLPs, batched over 4 queries; one hidden unit (tid) per thread
  float a[QB_], cc[QB_];
  #pragma unroll
  for (int jj=0;jj<QB_;jj++){ a[jj]=pb1[tid]; cc[jj]=cb1[tid]; }
  for (int c=0;c<C_;c++){
    float pwA = pw1[(size_t)c*HID_ + tid];
    float cwA = cw1[(size_t)c*HID_ + tid];
    #pragma unroll
    for (int jj=0;jj<QB_;jj++){
      float rv = tl[jj][c];
      a[jj] += rv*pwA; cc[jj] += rv*cwA;
    }
  }
  // hp/hc alias rows_l — safe: rows_l's last read was before the barrier above
  #pragma unroll
  for (int jj=0;jj<QB_;jj++){
    hp[jj][tid] = a[jj] * (1.f/(1.f+expf(-a[jj])));          // silu
    hc[jj][tid] = cc[jj] > 0.f ? cc[jj] : expm1f(cc[jj]);    // elu
  }
  __syncthreads();
  for (int jj=0;jj<QB_;jj++){
    if (tid < 128){
      int o = tid & 7, seg = tid >> 3;
      float p = 0.f;
      for (int j=seg*32; j<seg*32+32; j++) p += hp[jj][j]*pw2[j*8+o];
      redp[seg][o] = p;
    } else if (tid < 144){
      int seg = tid - 128;
      float p = 0.f;
      for (int j=seg*32; j<seg*32+32; j++) p += hc[jj][j]*cw2[j];
      redc[seg] = p;
    }
    __syncthreads();
    if (tid < 8){
      float sm = 0.f;
      for (int sg=0; sg<16; sg++) sm += redp[sg][tid];
      out_poly[((size_t)b*Q_+(q0+jj))*8 + tid] = sm + pb2[tid];
    }
    if (tid == 8){
      float sc = 0.f;
      for (int sg=0; sg<16; sg++) sc += redc[sg];
      sc += cb2[0];
      out_cls[b*Q_+(q0+jj)] = 1.f/(1.f+expf(-sc));
    }
    __syncthreads();
  }
}

// ---------------------------------------------------------------- launch
extern "C" void kernel_launch(void* const* d_in, const int* in_sizes, int n_in,
                              void* d_out, int out_size, void* d_ws, size_t ws_size,
                              hipStream_t stream){
  (void)in_sizes; (void)out_size;
  if (n_in < 29) return;
  const float* x       = (const float*)d_in[0];
  const float* qs_w1   = (const float*)d_in[1];
  const float* qs_b1   = (const float*)d_in[2];
  const float* qs_w2   = (const float*)d_in[3];
  const float* qs_b2   = (const float*)d_in[4];
  const float* rp_w1   = (const float*)d_in[5];
  const float* rp_b1   = (const float*)d_in[6];
  const float* rp_w2   = (const float*)d_in[7];
  const float* rp_b2   = (const float*)d_in[8];
  const float* mha_in_w  = (const float*)d_in[9];
  const float* mha_in_b  = (const float*)d_in[10];
  const float* mha_out_w = (const float*)d_in[11];
  const float* mha_out_b = (const float*)d_in[12];
  const float* dq_w    = (const float*)d_in[13];
  const float* dq_b    = (const float*)d_in[14];
  const float* dk_w    = (const float*)d_in[15];
  const float* dk_b    = (const float*)d_in[16];
  const float* dv_w    = (const float*)d_in[17];
  const float* dv_b    = (const float*)d_in[18];
  const float* ln1_g   = (const float*)d_in[19];
  const float* ln1_b   = (const float*)d_in[20];
  const float* cl_w1   = (const float*)d_in[21];
  const float* cl_b1   = (const float*)d_in[22];
  const float* cl_w2   = (const float*)d_in[23];
  const float* cl_b2   = (const float*)d_in[24];
  const float* po_w1   = (const float*)d_in[25];
  const float* po_b1   = (const float*)d_in[26];
  const float* po_w2   = (const float*)d_in[27];
  const float* po_b2   = (const float*)d_in[28];

  // -------- workspace layout; region R1 (0..9.8MB) is time-shared ----------
  constexpr size_t QKV1     = (size_t)B_*NH_*Q_*DH_;
  constexpr size_t SZ_R1    = 9830400;
  constexpr size_t OFF_IDXS = SZ_R1;
  constexpr size_t OFF_REFS = OFF_IDXS + 19200;
  constexpr size_t OFF_ATTO = OFF_REFS + 307200;
  constexpr size_t WS_NEED  = OFF_ATTO + 2457600;   // 12,614,400 bytes
  constexpr size_t OFF_XT   = WS_NEED;
  constexpr size_t SZ_XT    = (size_t)B_*HW_*C_*sizeof(float);  // 100,663,296
  constexpr size_t WS_NEED2 = OFF_XT + SZ_XT;       // 113,277,696 bytes
  if (ws_size < WS_NEED) return;
  const bool use_xt = (ws_size >= WS_NEED2);

  char* ws = (char*)d_ws;
  float* logits = (float*)(ws + 0);
  bf16*  qarr   = (bf16*) (ws + 0);
  bf16*  karr   = qarr + QKV1;
  bf16*  varr   = karr + QKV1;
  float* tgt    = (float*)(ws + 0);
  float* dqv    = (float*)(ws + 4915200);
  int*   idxs   = (int*)  (ws + OFF_IDXS);
  float* refs   = (float*)(ws + OFF_REFS);
  bf16*  att_o  = (bf16*) (ws + OFF_ATTO);
  float* xt     = (float*)(ws + OFF_XT);

  float* out_poly = (float*)d_out;               // [16][300][2][4] f32
  float* out_cls  = out_poly + B_*Q_*8;          // [16][300] f32

  if (use_xt){
    score_k<1><<<dim3(HW_/64, B_), 256, 0, stream>>>(x, qs_w1, qs_b1, qs_w2, qs_b2, logits, xt);
  } else {
    score_k<0><<<dim3(HW_/64, B_), 256, 0, stream>>>(x, qs_w1, qs_b1, qs_w2, qs_b2, logits, xt);
  }
  topk_k<<<B_, 1024, 0, stream>>>(logits, idxs);

  if (use_xt){
    qproj_k<1><<<B_*(Q_/QB_), 256, 0, stream>>>(x, xt, idxs, rp_w1, rp_b1, rp_w2, rp_b2,
                                                mha_in_w, mha_in_b, refs, qarr, karr, varr);
  } else {
    qproj_k<0><<<B_*(Q_/QB_), 256, 0, stream>>>(x, xt, idxs, rp_w1, rp_b1, rp_w2, rp_b2,
                                                mha_in_w, mha_in_b, refs, qarr, karr, varr);
  }
  attn_k<<<B_*NH_*4, 256, 0, stream>>>(qarr, karr, varr, att_o);
  if (use_xt){
    proj_ln_k<1><<<B_*(Q_/QB_), 256, 0, stream>>>(att_o, x, xt, idxs, mha_out_w, mha_out_b,
                                            ln1_g, ln1_b, dq_w, dq_b, tgt, dqv);
    deform_k<1><<<B_*(Q_/QB_), 512, 0, stream>>>(x, xt, refs, dqv, tgt,
                                           dk_w, dk_b, dv_w, dv_b,
                                           po_w1, po_b1, po_w2, po_b2,
                                           cl_w1, cl_b1, cl_w2, cl_b2,
                                           out_poly, out_cls);
  } else {
    proj_ln_k<0><<<B_*(Q_/QB_), 256, 0, stream>>>(att_o, x, xt, idxs, mha_out_w, mha_out_b,
                                            ln1_g, ln1_b, dq_w, dq_b, tgt, dqv);
    deform_k<0><<<B_*(Q_/QB_), 512, 0, stream>>>(x, xt, refs, dqv, tgt,
                                           dk_w, dk_b, dv_w, dv_b,
                                           po_w1, po_b1, po_w2, po_b2,
                                           cl_w1, cl_b1, cl_w2, cl_b2,
                                           out_poly, out_cls);
  }
}

// Round 19
// 1195.805 us; speedup vs baseline: 1.0037x; 1.0037x over previous
//
#include <hip/hip_runtime.h>
#include <hip/hip_bf16.h>
#include <math.h>

typedef __hip_bfloat16 bf16;

#define B_   16
#define C_   256
#define H_   64
#define W_   96
#define HW_  6144
#define Q_   300
#define NH_  8
#define DH_  32
#define HID_ 512
#define QB_  4                 // queries/block (qproj, proj_ln, deform)
#define SCALE_ 0.17677669529663687f   // 1/sqrt(32)

__device__ __forceinline__ float b2f(bf16 v){ return __bfloat162float(v); }
__device__ __forceinline__ bf16 f2b(float v){ return __float2bfloat16(v); }
__device__ __forceinline__ int clampi(int v, int lo, int hi){
  return v < lo ? lo : (v > hi ? hi : v);
}

// ---------------------------------------------------------------- scoring MLP (f32, register-tiled)
// 8x8 register tile; hidden in 2 passes of 256; kt-tiles of 16 channels.
// XT=1: writes xt [B,HW,C] as a side-effect of pass-0 staging. Store mapping
// rr=tid>>2, c4=tid&3: 4 consecutive lanes fill one 64B line (one row's
// 16-channel slice) -> fully coalesced wave stores (R16's rr=tid&63 mapping
// had each lane 1KB apart: 64 partial-line writes/wave, +143us).
// Bitwise-identical xt (same staged values).
template<int XT>
__global__ __launch_bounds__(256) void score_k(const float* __restrict__ x,
    const float* __restrict__ w1, const float* __restrict__ b1,
    const float* __restrict__ w2, const float* __restrict__ b2,
    float* __restrict__ logits, float* __restrict__ xt){
  int b = blockIdx.y, hw0 = blockIdx.x*64;
  int tid = threadIdx.x;
  int tc = tid & 31;        // hidden group 0..31 (2x4 wide)
  int tr = tid >> 5;        // hw group 0..7 (8 wide)
  __shared__ float xs[16][68];
  __shared__ float wsl[16][256];
  float (*red)[33] = (float(*)[33])wsl;   // alias: used only after final barrier
  float part[8];
  #pragma unroll
  for (int i=0;i<8;i++) part[i]=0.f;
  for (int pass=0; pass<2; ++pass){
    float acc[8][8];
    #pragma unroll
    for (int i=0;i<8;i++)
      #pragma unroll
      for (int j=0;j<8;j++) acc[i][j]=0.f;
    for (int kt=0; kt<16; ++kt){
      // stage x tile [16 c][64 hw]: 256 float4, 1 per thread
      {
        int e = tid;                    // float4 index 0..255
        int rr4 = e & 15, kk = e >> 4;  // 16 f4 per row, kk 0..15
        *reinterpret_cast<float4*>(&xs[kk][rr4*4]) =
          *reinterpret_cast<const float4*>(&x[(size_t)(b*C_ + kt*16+kk)*HW_ + hw0 + rr4*4]);
      }
      // stage w1 tile [16 c][256 hid]: 1024 float4, 4 per thread
      #pragma unroll
      for (int i=0;i<4;i++){
        int e = tid + i*256;            // float4 index 0..1023
        int jj4 = e & 63, kk = e >> 6;  // 64 f4 per row, kk 0..15
        *reinterpret_cast<float4*>(&wsl[kk][jj4*4]) =
          *reinterpret_cast<const float4*>(&w1[(size_t)(kt*16+kk)*HID_ + pass*256 + jj4*4]);
      }
      __syncthreads();
      // pass-0 side effect: write this tile transposed to xt.
      // rr=tid>>2 (row), c4=tid&3 (16B chunk): lanes 4k..4k+3 fill the full
      // 64B line of row rr=k -> wave issues 16 complete-line stores.
      if (XT && pass==0){
        int rr = tid >> 2, c4 = tid & 3;
        float4 v;
        v.x = xs[c4*4+0][rr]; v.y = xs[c4*4+1][rr];
        v.z = xs[c4*4+2][rr]; v.w = xs[c4*4+3][rr];
        *reinterpret_cast<float4*>(&xt[((size_t)b*HW_ + hw0 + rr)*C_ + kt*16 + c4*4]) = v;
      }
      #pragma unroll
      for (int k=0;k<16;k++){
        float4 a0 = *reinterpret_cast<float4*>(&xs[k][tr*8]);
        float4 a1 = *reinterpret_cast<float4*>(&xs[k][tr*8+4]);
        float4 w0 = *reinterpret_cast<float4*>(&wsl[k][tc*4]);
        float4 w4 = *reinterpret_cast<float4*>(&wsl[k][128 + tc*4]);
        float aa[8] = {a0.x,a0.y,a0.z,a0.w,a1.x,a1.y,a1.z,a1.w};
        float ww[8] = {w0.x,w0.y,w0.z,w0.w,w4.x,w4.y,w4.z,w4.w};
        #pragma unroll
        for (int i=0;i<8;i++)
          #pragma unroll
          for (int j=0;j<8;j++)
            acc[i][j] += aa[i]*ww[j];
      }
      __syncthreads();
    }
    // epilogue for this pass: elu + dot with w2 into part[i]
    #pragma unroll
    for (int j=0;j<8;j++){
      int col = (j < 4) ? (tc*4 + j) : (128 + tc*4 + (j-4));
      int jg = pass*256 + col;
      float bb = b1[jg], w2v = w2[jg];
      #pragma unroll
      for (int i=0;i<8;i++){
        float h = acc[i][j] + bb;
        h = h > 0.f ? h : expm1f(h);     // elu
        part[i] += h * w2v;
      }
    }
  }
  // reduce part[8] over the 32 tc groups (red aliases wsl; all reads done)
  #pragma unroll
  for (int i=0;i<8;i++) red[tr*8+i][tc] = part[i];
  __syncthreads();
  if (tid < 64){
    float s = 0.f;
    for (int t=0;t<32;t++) s += red[tid][t];
    logits[(size_t)b*HW_ + hw0 + tid] = s + b2[0];
  }
}

// ---------------------------------------------------------------- top-k (300 of 6144), f32
__global__ __launch_bounds__(1024) void topk_k(const float* __restrict__ logits,
                                               int* __restrict__ idxs){
  int b = blockIdx.x, tid = threadIdx.x;
  __shared__ unsigned long long keys[8192];
  for (int i = tid; i < 8192; i += 1024){
    unsigned long long key = 0ull;                 // pad sorts last
    if (i < HW_){
      float v = logits[(size_t)b*HW_ + i];
      unsigned u = __float_as_uint(v);
      unsigned m = (u & 0x80000000u) ? ~u : (u ^ 0x80000000u);
      if (!(v == v)) m = 0u;                       // NaN sorts last
      key = ((unsigned long long)m << 32) | (unsigned)(HW_ - 1 - i);
    }
    keys[i] = key;
  }
  __syncthreads();
  for (int k = 2; k <= 8192; k <<= 1){
    for (int j = k >> 1; j >= 1; j >>= 1){
      for (int i = tid; i < 8192; i += 1024){
        int l = i ^ j;
        if (l > i){
          unsigned long long a = keys[i], c = keys[l];
          bool sw = ((i & k) == 0) ? (a < c) : (a > c);   // descending overall
          if (sw){ keys[i] = c; keys[l] = a; }
        }
      }
      __syncthreads();
    }
  }
  if (tid < Q_){
    int idx = HW_ - 1 - (int)(keys[tid] & 0xFFFFFFFFull);
    idxs[b*Q_ + tid] = idx;
  }
}

// ---------------------------------------------------------------- fused rp-refs + MHA qkv (4 queries/block)
template<int XT>
__global__ __launch_bounds__(256) void qproj_k(const float* __restrict__ x,
    const float* __restrict__ xt,
    const int* __restrict__ idxs,
    const float* __restrict__ rw1, const float* __restrict__ rb1,
    const float* __restrict__ rw2, const float* __restrict__ rb2,
    const float* __restrict__ mw,  const float* __restrict__ mb,
    float* __restrict__ refs,
    bf16* __restrict__ qarr, bf16* __restrict__ karr, bf16* __restrict__ varr){
  int blk = blockIdx.x;
  int b = blk/(Q_/QB_), q0 = (blk%(Q_/QB_))*QB_;
  int tid = threadIdx.x;
  __shared__ float rowl[QB_][C_];
  __shared__ float hl[QB_][HID_];
  __shared__ float red[16][17];
  int idxv[QB_];
  #pragma unroll
  for (int j=0;j<QB_;j++) idxv[j] = clampi(idxs[b*Q_+q0+j], 0, HW_-1);
  #pragma unroll
  for (int j=0;j<QB_;j++){
    if (XT) rowl[j][tid] = xt[((size_t)b*HW_ + idxv[j])*C_ + tid];
    else    rowl[j][tid] = x[((size_t)b*C_ + tid)*HW_ + idxv[j]];
  }
  __syncthreads();
  // rp hidden (no activation between rp layers)
  float h0[QB_], h1[QB_];
  #pragma unroll
  for (int j=0;j<QB_;j++){ h0[j]=rb1[tid]; h1[j]=rb1[tid+256]; }
  for (int c=0;c<C_;c++){
    float wv0 = rw1[(size_t)c*HID_ + tid];
    float wv1 = rw1[(size_t)c*HID_ + tid + 256];
    #pragma unroll
    for (int j=0;j<QB_;j++){
      float rv = rowl[j][c];
      h0[j] += rv*wv0; h1[j] += rv*wv1;
    }
  }
  #pragma unroll
  for (int j=0;j<QB_;j++){ hl[j][tid]=h0[j]; hl[j][tid+256]=h1[j]; }
  // qkv projection
  float aq[QB_], ak[QB_], av[QB_];
  #pragma unroll
  for (int j=0;j<QB_;j++){ aq[j]=mb[tid]; ak[j]=mb[tid+256]; av[j]=mb[tid+512]; }
  for (int c=0;c<C_;c++){
    const float* wr = mw + (size_t)c*768;
    float w0 = wr[tid], w1v = wr[tid+256], w2v = wr[tid+512];
    #pragma unroll
    for (int j=0;j<QB_;j++){
      float rv = rowl[j][c];
      aq[j] += rv*w0; ak[j] += rv*w1v; av[j] += rv*w2v;
    }
  }
  int h = tid>>5, d = tid&31;
  #pragma unroll
  for (int j=0;j<QB_;j++){
    size_t o = (((size_t)b*NH_+h)*Q_+(q0+j))*DH_ + d;
    qarr[o]=f2b(aq[j]); karr[o]=f2b(ak[j]); varr[o]=f2b(av[j]);
  }
  __syncthreads();   // hl ready
  // rp second layer: 16 outputs per query
  int o = tid & 15, seg = tid >> 4;
  for (int j=0;j<QB_;j++){
    float p = 0.f;
    for (int jj=seg*32; jj<seg*32+32; jj++) p += hl[j][jj]*rw2[jj*16+o];
    red[seg][o] = p;
    __syncthreads();
    if (tid < 16){
      float s = 0.f;
      for (int sg=0; sg<16; sg++) s += red[sg][tid];
      refs[((size_t)b*Q_+(q0+j))*16 + tid] = tanhf(s + rb2[tid]);
    }
    __syncthreads();
  }
}

// ---------------------------------------------------------------- self-attention (per b,h; split in 4)
__global__ __launch_bounds__(256) void attn_k(const bf16* __restrict__ qarr,
    const bf16* __restrict__ karr, const bf16* __restrict__ varr,
    bf16* __restrict__ att_o){
  int blk = blockIdx.x; int bh = blk >> 2, part = blk & 3;
  int tid = threadIdx.x, rg = tid >> 5, lane = tid & 31;
  __shared__ bf16 kk[Q_][34];
  __shared__ bf16 vv[Q_][34];
  __shared__ float ps[8][304];
  __shared__ float qsl[8][32];
  const bf16* kb = karr + (size_t)bh*Q_*DH_;
  const bf16* vb = varr + (size_t)bh*Q_*DH_;
  const bf16* qb = qarr + (size_t)bh*Q_*DH_;
  for (int e=tid; e<Q_*DH_; e+=256){
    int k = e >> 5, d = e & 31;
    kk[k][d] = kb[e];
    vv[k][d] = vb[e];
  }
  __syncthreads();
  int b = bh >> 3, h = bh & 7;
  int rbase = part*75;
  for (int p0=0; p0<75; p0+=8){
    int rr = p0 + rg;
    bool act = rr < 75;
    int r = rbase + (act ? rr : 0);
    float qd = act ? b2f(qb[r*DH_ + lane]) : 0.f;
    qsl[rg][lane] = qd;
    __syncthreads();
    float lmax = -1e30f;
    for (int k=lane; k<Q_; k+=32){
      float s = 0.f;
      #pragma unroll
      for (int d=0; d<DH_; d++) s += qsl[rg][d]*b2f(kk[k][d]);
      s *= SCALE_;
      ps[rg][k] = s;
      lmax = fmaxf(lmax, s);
    }
    #pragma unroll
    for (int off=16; off>=1; off>>=1) lmax = fmaxf(lmax, __shfl_xor(lmax, off, 32));
    float lsum = 0.f;
    for (int k=lane; k<Q_; k+=32){
      float e = expf(ps[rg][k] - lmax);
      ps[rg][k] = e;
      lsum += e;
    }
    #pragma unroll
    for (int off=16; off>=1; off>>=1) lsum += __shfl_xor(lsum, off, 32);
    __syncthreads();
    float out = 0.f;
    for (int k=0;k<Q_;k++) out += ps[rg][k]*b2f(vv[k][lane]);
    if (act) att_o[((size_t)b*Q_ + r)*C_ + h*DH_ + lane] = f2b(out / lsum);
    __syncthreads();
  }
}

// ---------------------------------------------------------------- out-proj + residual + LN + dq (4 queries/block)
template<int XT>
__global__ __launch_bounds__(256) void proj_ln_k(const bf16* __restrict__ att_o,
    const float* __restrict__ x, const float* __restrict__ xt,
    const int* __restrict__ idxs,
    const float* __restrict__ ow, const float* __restrict__ ob,
    const float* __restrict__ g,  const float* __restrict__ beta,
    const float* __restrict__ dqw, const float* __restrict__ dqb,
    float* __restrict__ tgt, float* __restrict__ dqv){
  int blk = blockIdx.x, tid = threadIdx.x;
  int b = blk/(Q_/QB_), q0 = (blk%(Q_/QB_))*QB_;
  __shared__ float ol[QB_][C_];
  __shared__ float yl[QB_][C_];
  __shared__ float rs[QB_][4], rs2[QB_][4];
  #pragma unroll
  for (int j=0;j<QB_;j++)
    ol[j][tid] = b2f(att_o[((size_t)(b*Q_+q0+j))*C_ + tid]);
  __syncthreads();
  float acc[QB_];
  #pragma unroll
  for (int j=0;j<QB_;j++) acc[j] = ob[tid];
  for (int c=0;c<C_;c++){
    float w = ow[(size_t)c*C_+tid];
    #pragma unroll
    for (int j=0;j<QB_;j++) acc[j] += ol[j][c]*w;
  }
  float tv[QB_];
  #pragma unroll
  for (int j=0;j<QB_;j++){
    int idx = clampi(idxs[b*Q_+q0+j], 0, HW_-1);
    float resid;
    if (XT) resid = xt[((size_t)b*HW_ + idx)*C_ + tid];
    else    resid = x[((size_t)b*C_ + tid)*HW_ + idx];
    tv[j] = resid + acc[j];
  }
  // LN per query (4 independent 256-wide reductions)
  #pragma unroll
  for (int j=0;j<QB_;j++){
    float s = tv[j], s2 = tv[j]*tv[j];
    #pragma unroll
    for (int off=32; off>=1; off>>=1){
      s  += __shfl_xor(s,  off, 64);
      s2 += __shfl_xor(s2, off, 64);
    }
    if ((tid&63)==0){ rs[j][tid>>6]=s; rs2[j][tid>>6]=s2; }
  }
  __syncthreads();
  #pragma unroll
  for (int j=0;j<QB_;j++){
    float ts=0.f, ts2=0.f;
    #pragma unroll
    for (int w=0;w<4;w++){ ts+=rs[j][w]; ts2+=rs2[j][w]; }
    float mu = ts*(1.f/256.f);
    float var = ts2*(1.f/256.f) - mu*mu;
    if (!(var > 0.f)) var = 0.f;
    float y = (tv[j]-mu)*rsqrtf(var+1e-5f)*g[tid] + beta[tid];
    tgt[((size_t)(b*Q_+q0+j))*C_ + tid] = y;
    yl[j][tid] = y;
  }
  __syncthreads();
  float a2[QB_];
  #pragma unroll
  for (int j=0;j<QB_;j++) a2[j] = dqb[tid];
  for (int c=0;c<C_;c++){
    float w = dqw[(size_t)c*C_+tid];
    #pragma unroll
    for (int j=0;j<QB_;j++) a2[j] += yl[j][c]*w;
  }
  #pragma unroll
  for (int j=0;j<QB_;j++)
    dqv[((size_t)(b*Q_+q0+j))*C_ + tid] = a2[j];
}

// ---------------------------------------------------------------- deformable attn + final MLPs
// R10/R11-exact — measured-best deform (370-383us across 9 config A/Bs).
template<int XT>
__global__ __launch_bounds__(512) void deform_k(const float* __restrict__ x,
    const float* __restrict__ xt,
    const float* __restrict__ refs, const float* __restrict__ dqv,
    const float* __restrict__ tgt,
    const float* __restrict__ dkw, const float* __restrict__ dkb,
    const float* __restrict__ dvw, const float* __restrict__ dvb,
    const float* __restrict__ pw1, const float* __restrict__ pb1,
    const float* __restrict__ pw2, const float* __restrict__ pb2,
    const float* __restrict__ cw1, const float* __restrict__ cb1,
    const float* __restrict__ cw2, const float* __restrict__ cb2,
    float* __restrict__ out_poly, float* __restrict__ out_cls){
  int blk = blockIdx.x; int b = blk/(Q_/QB_), qg = blk%(Q_/QB_);
  int q0 = qg*QB_;
  int tid = threadIdx.x;
  int col = tid & 255;
  int half = tid >> 8;                               // 0 -> queries 0,1; 1 -> queries 2,3
  __shared__ float smem_u[32*C_];                    // 32KB union region
  float (*rows_l)[C_]  = (float(*)[C_])smem_u;       // [32][256]
  float (*hp)[HID_]    = (float(*)[HID_])smem_u;     // [QB][512] (aliased)
  float (*hc)[HID_]    = (float(*)[HID_])(smem_u + QB_*HID_);
  __shared__ float tl[QB_][C_];        // 4KB
  __shared__ float grefs[32][2];
  __shared__ float redp[16][8];
  __shared__ float redc[16];
  // prefetch refs for all 32 rows (one float per thread, parallel)
  if (tid < 64){
    int rloc = tid >> 1, comp = tid & 1;
    int r = qg*32 + rloc;
    int n = r/Q_, q = r - n*Q_;
    grefs[rloc][comp] = refs[(((size_t)b*Q_+q)*8+n)*2 + comp];
  }
  __syncthreads();
  const float* xc  = x  + ((size_t)b*C_ + col)*HW_;
  const float* xbt = xt + (size_t)b*HW_*C_;
  // gather this half's 16 bilinear-sampled rows (channel col of each)
  for (int i=0; i<16; ++i){
    int rloc = half*16 + i;
    float gx = grefs[rloc][0];
    float gy = grefs[rloc][1];
    if (!(gx > -2.f && gx < 2.f)) gx = 0.f;
    if (!(gy > -2.f && gy < 2.f)) gy = 0.f;
    float ix = (gx + 1.f)*48.f - 0.5f;    // W/2
    float iy = (gy + 1.f)*32.f - 0.5f;    // H/2
    float fx = floorf(ix), fy = floorf(iy);
    int x0 = (int)fx, y0 = (int)fy;
    float wx1 = ix - fx, wy1 = iy - fy;
    float wx0 = 1.f - wx1, wy0 = 1.f - wy1;
    float v = 0.f;
    if (XT){
      if (y0   >= 0 && y0   < H_ && x0   >= 0 && x0   < W_) v += wy0*wx0*xbt[(size_t)(y0*W_+x0)*C_ + col];
      if (y0   >= 0 && y0   < H_ && x0+1 >= 0 && x0+1 < W_) v += wy0*wx1*xbt[(size_t)(y0*W_+x0+1)*C_ + col];
      if (y0+1 >= 0 && y0+1 < H_ && x0   >= 0 && x0   < W_) v += wy1*wx0*xbt[(size_t)((y0+1)*W_+x0)*C_ + col];
      if (y0+1 >= 0 && y0+1 < H_ && x0+1 >= 0 && x0+1 < W_) v += wy1*wx1*xbt[(size_t)((y0+1)*W_+x0+1)*C_ + col];
    } else {
      if (y0   >= 0 && y0   < H_ && x0   >= 0 && x0   < W_) v += wy0*wx0*xc[y0*W_+x0];
      if (y0   >= 0 && y0   < H_ && x0+1 >= 0 && x0+1 < W_) v += wy0*wx1*xc[y0*W_+x0+1];
      if (y0+1 >= 0 && y0+1 < H_ && x0   >= 0 && x0   < W_) v += wy1*wx0*xc[(y0+1)*W_+x0];
      if (y0+1 >= 0 && y0+1 < H_ && x0+1 >= 0 && x0+1 < W_) v += wy1*wx1*xc[(y0+1)*W_+x0+1];
    }
    rows_l[rloc][col] = v;
  }
  __syncthreads();
  // dk/dv projection: this half's 16 rows, register accumulators, c-loop x4
  float ka[16], va[16];
  float kbb = dkb[col], vbb = dvb[col];
  #pragma unroll
  for (int rr=0; rr<16; ++rr){ ka[rr]=kbb; va[rr]=vbb; }
  for (int c=0; c<C_; c+=4){
    float wk0 = dkw[(size_t)(c+0)*C_+col], wk1 = dkw[(size_t)(c+1)*C_+col];
    float wk2 = dkw[(size_t)(c+2)*C_+col], wk3 = dkw[(size_t)(c+3)*C_+col];
    float wv0 = dvw[(size_t)(c+0)*C_+col], wv1 = dvw[(size_t)(c+1)*C_+col];
    float wv2 = dvw[(size_t)(c+2)*C_+col], wv3 = dvw[(size_t)(c+3)*C_+col];
    #pragma unroll
    for (int rr=0; rr<16; ++rr){
      float4 rv = *reinterpret_cast<float4*>(&rows_l[half*16+rr][c]);   // LDS broadcast
      ka[rr] += rv.x*wk0 + rv.y*wk1 + rv.z*wk2 + rv.w*wk3;
      va[rr] += rv.x*wv0 + rv.y*wv1 + rv.z*wv2 + rv.w*wv3;
    }
  }
  // attention: this half's 2 queries (head = col>>5; 32-lane reduce is intra-head)
  #pragma unroll
  for (int jq=0; jq<2; ++jq){
    int jj = half*2 + jq;
    int q2 = q0 + jj;
    float qd = dqv[((size_t)b*Q_+q2)*C_ + col];
    float s[8];
    #pragma unroll
    for (int n=0;n<8;n++){
      float t_ = qd * ka[jq*8+n];
      #pragma unroll
      for (int off=16; off>=1; off>>=1) t_ += __shfl_xor(t_, off, 32);
      s[n] = t_ * SCALE_;
    }
    float m = s[0];
    #pragma unroll
    for (int n=1;n<8;n++) m = fmaxf(m, s[n]);
    float e[8], sum = 0.f;
    #pragma unroll
    for (int n=0;n<8;n++){ e[n] = expf(s[n]-m); sum += e[n]; }
    float inv = 1.f/sum;
    float out = 0.f;
    #pragma unroll
    for (int n=0;n<8;n++) out += e[n]*inv*va[jq*8+n];
    tl[jj][col] = tgt[((size_t)b*Q_+q2)*C_ + col] + out;
  }
  __syncthreads();   // orders: all rows_l reads done; tl ready for all 4 queries
  // final MLPs, batched over 4 queries; one hidden unit (tid) per thread
  float a[QB_], cc[QB_];
  #pragma unroll
  for (int jj=0;jj<QB_;jj++){ a[jj]=pb1[tid]; cc[jj]=cb1[tid]; }
  for (int c=0;c<C_;c++){
    float pwA = pw1[(size_t)c*HID_ + tid];
    float cwA = cw1[(size_t)c*HID_ + tid];
    #pragma unroll
    for (int jj=0;jj<QB_;jj++){
      float rv = tl[jj][c];
      a[jj] += rv*pwA; cc[jj] += rv*cwA;
    }
  }
  // hp/hc alias rows_l — safe: rows_l's last read was before the barrier above
  #pragma unroll
  for (int jj=0;jj<QB_;jj++){
    hp[jj][tid] = a[jj] * (1.f/(1.f+expf(-a[jj])));          // silu
    hc[jj][tid] = cc[jj] > 0.f ? cc[jj] : expm1f(cc[jj]);    // elu
  }
  __syncthreads();
  for (int jj=0;jj<QB_;jj++){
    if (tid < 128){
      int o = tid & 7, seg = tid >> 3;
      float p = 0.f;
      for (int j=seg*32; j<seg*32+32; j++) p += hp[jj][j]*pw2[j*8+o];
      redp[seg][o] = p;
    } else if (tid < 144){
      int seg = tid - 128;
      float p = 0.f;
      for (int j=seg*32; j<seg*32+32; j++) p += hc[jj][j]*cw2[j];
      redc[seg] = p;
    }
    __syncthreads();
    if (tid < 8){
      float sm = 0.f;
      for (int sg=0; sg<16; sg++) sm += redp[sg][tid];
      out_poly[((size_t)b*Q_+(q0+jj))*8 + tid] = sm + pb2[tid];
    }
    if (tid == 8){
      float sc = 0.f;
      for (int sg=0; sg<16; sg++) sc += redc[sg];
      sc += cb2[0];
      out_cls[b*Q_+(q0+jj)] = 1.f/(1.f+expf(-sc));
    }
    __syncthreads();
  }
}

// ---------------------------------------------------------------- launch
extern "C" void kernel_launch(void* const* d_in, const int* in_sizes, int n_in,
                              void* d_out, int out_size, void* d_ws, size_t ws_size,
                              hipStream_t stream){
  (void)in_sizes; (void)out_size;
  if (n_in < 29) return;
  const float* x       = (const float*)d_in[0];
  const float* qs_w1   = (const float*)d_in[1];
  const float* qs_b1   = (const float*)d_in[2];
  const float* qs_w2   = (const float*)d_in[3];
  const float* qs_b2   = (const float*)d_in[4];
  const float* rp_w1   = (const float*)d_in[5];
  const float* rp_b1   = (const float*)d_in[6];
  const float* rp_w2   = (const float*)d_in[7];
  const float* rp_b2   = (const float*)d_in[8];
  const float* mha_in_w  = (const float*)d_in[9];
  const float* mha_in_b  = (const float*)d_in[10];
  const float* mha_out_w = (const float*)d_in[11];
  const float* mha_out_b = (const float*)d_in[12];
  const float* dq_w    = (const float*)d_in[13];
  const float* dq_b    = (const float*)d_in[14];
  const float* dk_w    = (const float*)d_in[15];
  const float* dk_b    = (const float*)d_in[16];
  const float* dv_w    = (const float*)d_in[17];
  const float* dv_b    = (const float*)d_in[18];
  const float* ln1_g   = (const float*)d_in[19];
  const float* ln1_b   = (const float*)d_in[20];
  const float* cl_w1   = (const float*)d_in[21];
  const float* cl_b1   = (const float*)d_in[22];
  const float* cl_w2   = (const float*)d_in[23];
  const float* cl_b2   = (const float*)d_in[24];
  const float* po_w1   = (const float*)d_in[25];
  const float* po_b1   = (const float*)d_in[26];
  const float* po_w2   = (const float*)d_in[27];
  const float* po_b2   = (const float*)d_in[28];

  // -------- workspace layout; region R1 (0..9.8MB) is time-shared ----------
  constexpr size_t QKV1     = (size_t)B_*NH_*Q_*DH_;
  constexpr size_t SZ_R1    = 9830400;
  constexpr size_t OFF_IDXS = SZ_R1;
  constexpr size_t OFF_REFS = OFF_IDXS + 19200;
  constexpr size_t OFF_ATTO = OFF_REFS + 307200;
  constexpr size_t WS_NEED  = OFF_ATTO + 2457600;   // 12,614,400 bytes
  constexpr size_t OFF_XT   = WS_NEED;
  constexpr size_t SZ_XT    = (size_t)B_*HW_*C_*sizeof(float);  // 100,663,296
  constexpr size_t WS_NEED2 = OFF_XT + SZ_XT;       // 113,277,696 bytes
  if (ws_size < WS_NEED) return;
  const bool use_xt = (ws_size >= WS_NEED2);

  char* ws = (char*)d_ws;
  float* logits = (float*)(ws + 0);
  bf16*  qarr   = (bf16*) (ws + 0);
  bf16*  karr   = qarr + QKV1;
  bf16*  varr   = karr + QKV1;
  float* tgt    = (float*)(ws + 0);
  float* dqv    = (float*)(ws + 4915200);
  int*   idxs   = (int*)  (ws + OFF_IDXS);
  float* refs   = (float*)(ws + OFF_REFS);
  bf16*  att_o  = (bf16*) (ws + OFF_ATTO);
  float* xt     = (float*)(ws + OFF_XT);

  float* out_poly = (float*)d_out;               // [16][300][2][4] f32
  float* out_cls  = out_poly + B_*Q_*8;          // [16][300] f32

  if (use_xt){
    score_k<1><<<dim3(HW_/64, B_), 256, 0, stream>>>(x, qs_w1, qs_b1, qs_w2, qs_b2, logits, xt);
  } else {
    score_k<0><<<dim3(HW_/64, B_), 256, 0, stream>>>(x, qs_w1, qs_b1, qs_w2, qs_b2, logits, xt);
  }
  topk_k<<<B_, 1024, 0, stream>>>(logits, idxs);

  if (use_xt){
    qproj_k<1><<<B_*(Q_/QB_), 256, 0, stream>>>(x, xt, idxs, rp_w1, rp_b1, rp_w2, rp_b2,
                                                mha_in_w, mha_in_b, refs, qarr, karr, varr);
  } else {
    qproj_k<0><<<B_*(Q_/QB_), 256, 0, stream>>>(x, xt, idxs, rp_w1, rp_b1, rp_w2, rp_b2,
                                                mha_in_w, mha_in_b, refs, qarr, karr, varr);
  }
  attn_k<<<B_*NH_*4, 256, 0, stream>>>(qarr, karr, varr, att_o);
  if (use_xt){
    proj_ln_k<1><<<B_*(Q_/QB_), 256, 0, stream>>>(att_o, x, xt, idxs, mha_out_w, mha_out_b,
                                            ln1_g, ln1_b, dq_w, dq_b, tgt, dqv);
    deform_k<1><<<B_*(Q_/QB_), 512, 0, stream>>>(x, xt, refs, dqv, tgt,
                                           dk_w, dk_b, dv_w, dv_b,
                                           po_w1, po_b1, po_w2, po_b2,
                                           cl_w1, cl_b1, cl_w2, cl_b2,
                                           out_poly, out_cls);
  } else {
    proj_ln_k<0><<<B_*(Q_/QB_), 256, 0, stream>>>(att_o, x, xt, idxs, mha_out_w, mha_out_b,
                                            ln1_g, ln1_b, dq_w, dq_b, tgt, dqv);
    deform_k<0><<<B_*(Q_/QB_), 512, 0, stream>>>(x, xt, refs, dqv, tgt,
                                           dk_w, dk_b, dv_w, dv_b,
                                           po_w1, po_b1, po_w2, po_b2,
                                           cl_w1, cl_b1, cl_w2, cl_b2,
                                           out_poly, out_cls);
  }
}